// Round 5
// baseline (1435.082 us; speedup 1.0000x reference)
//
#include <hip/hip_runtime.h>
#include <cstdint>
#include <cstddef>

// Problem constants
#define BATCH   8
#define KPTS    8192
#define NPT     1024
#define NSAMP   16
#define RAD2    0.09f

typedef float f32x2 __attribute__((ext_vector_type(2)));

// DPP max-reduce step for packed u64 (hi=float bits, lo=8191-idx).
// bound_ctrl=true -> out-of-range source lanes read 0 (neutral for unsigned max).
template <int CTRL>
__device__ __forceinline__ unsigned long long dpp_max_step(unsigned long long v) {
    unsigned int lo = (unsigned int)v, hi = (unsigned int)(v >> 32);
    unsigned int lo2 = (unsigned int)__builtin_amdgcn_update_dpp(0, (int)lo, CTRL, 0xf, 0xf, true);
    unsigned int hi2 = (unsigned int)__builtin_amdgcn_update_dpp(0, (int)hi, CTRL, 0xf, 0xf, true);
    unsigned long long o = ((unsigned long long)hi2 << 32) | lo2;
    return o > v ? o : v;
}

// ---------------------------------------------------------------------------
// Fused FPS + F0 dispatch, 512 threads/block.
// Blocks 0..7: FPS (one per batch, 16 pts/thread -> coord arrays fit in VGPRs;
//   round-4 post-mortem: 32 pts/thread forced LDS re-reads, ~1500 cyc/iter).
// Blocks 8..519: F0 pre-gather GEMM tiles (128x128, 4x8 acc/thread).
// FPS: xyz in LDS (SoA broadcast), packed-u64 DPP argmax (value + smallest
// index = NumPy first-occurrence), ONE barrier/iter with ping-pong slots.
// Distance math float2 IEEE contract(off) == NumPy rounding exactly.
// ---------------------------------------------------------------------------
__global__ __launch_bounds__(512, 1) void fps_f0_kernel(
    const float* __restrict__ xyz, float* __restrict__ new_xyz,
    const float* __restrict__ feats, const float* __restrict__ w0,
    float* __restrict__ f0out) {
    __shared__ float xs[KPTS], ys[KPTS], zs[KPTS];               // 96 KB (fps)
    __shared__ __align__(16) unsigned long long wslot[2][8];
    __shared__ float As[16 * 128];                                // f0
    __shared__ float Bs[16 * 130];                                // f0

    const int tid = threadIdx.x;

    if (blockIdx.x >= 8) {
        // ---------------- F0 GEMM: F0[b,p,o] = sum_c feats[b,c,p]*w0[o,3+c]
        const int bid = blockIdx.x - 8;
        const int b   = bid >> 6;
        const int p0  = (bid & 63) << 7;
        const int rb  = (tid >> 4) << 2;  // 4 rows (points), 0..124
        const int ob  = tid & 15;         // col base; cols = ob + 16*c
        const float* fb = feats + (size_t)b * 256 * KPTS;

        float acc[4][8];
#pragma unroll
        for (int r = 0; r < 4; ++r)
#pragma unroll
            for (int c = 0; c < 8; ++c) acc[r][c] = 0.f;

        for (int k0 = 0; k0 < 256; k0 += 16) {
#pragma unroll
            for (int i = 0; i < 4; ++i) {
                int e = tid + (i << 9);
                int kk = e >> 7, pc = e & 127;
                As[kk * 128 + pc] = fb[(size_t)(k0 + kk) * KPTS + p0 + pc];
            }
#pragma unroll
            for (int i = 0; i < 4; ++i) {
                int e = tid + (i << 9);
                int o = e >> 4, kk = e & 15;
                Bs[kk * 130 + o] = w0[o * 259 + 3 + k0 + kk];
            }
            __syncthreads();
#pragma unroll
            for (int kk = 0; kk < 16; ++kk) {
                float a[4], wvv[8];
#pragma unroll
                for (int r = 0; r < 4; ++r) a[r] = As[kk * 128 + rb + r];
#pragma unroll
                for (int c = 0; c < 8; ++c) wvv[c] = Bs[kk * 130 + ob + (c << 4)];
#pragma unroll
                for (int r = 0; r < 4; ++r)
#pragma unroll
                    for (int c = 0; c < 8; ++c) acc[r][c] = fmaf(a[r], wvv[c], acc[r][c]);
            }
            __syncthreads();
        }
#pragma unroll
        for (int r = 0; r < 4; ++r) {
            float* outp = f0out + ((size_t)b * KPTS + p0 + rb + r) * 128 + ob;
#pragma unroll
            for (int c = 0; c < 8; ++c) outp[c << 4] = acc[r][c];
        }
        return;
    }

    // ---------------- FPS ----------------
    {
#pragma clang fp contract(off)
        const int b = blockIdx.x;
        const float* xb = xyz + (size_t)b * KPTS * 3;

        for (int i = tid; i < KPTS; i += 512) {
            xs[i] = xb[i * 3 + 0];
            ys[i] = xb[i * 3 + 1];
            zs[i] = xb[i * 3 + 2];
        }
        __syncthreads();

        const int base = tid << 4;  // 16 points per thread (8 float2 pairs)
        f32x2 px[8], py[8], pz[8], dmn[8];
#pragma unroll
        for (int j = 0; j < 8; ++j) {
            int i0 = base + (j << 1);
            px[j] = (f32x2){xs[i0], xs[i0 + 1]};
            py[j] = (f32x2){ys[i0], ys[i0 + 1]};
            pz[j] = (f32x2){zs[i0], zs[i0 + 1]};
            dmn[j] = (f32x2){1e10f, 1e10f};
        }

        int far = 0;
        for (int it = 0; it < NPT; ++it) {
            const float cx = xs[far], cy = ys[far], cz = zs[far];
            if (tid == 0) {
                float* o = new_xyz + ((size_t)b * NPT + it) * 3;
                o[0] = cx; o[1] = cy; o[2] = cz;
            }
            const f32x2 cx2 = (f32x2){cx, cx};
            const f32x2 cy2 = (f32x2){cy, cy};
            const f32x2 cz2 = (f32x2){cz, cz};

            f32x2 mm = (f32x2){-1.0f, -1.0f};
#pragma unroll
            for (int j = 0; j < 8; ++j) {
                f32x2 dx = px[j] - cx2;
                f32x2 dy = py[j] - cy2;
                f32x2 dz = pz[j] - cz2;
                f32x2 d  = (dx * dx + dy * dy) + dz * dz;  // rounded squares, seq adds
                f32x2 nd = __builtin_elementwise_min(dmn[j], d);
                dmn[j] = nd;
                mm = __builtin_elementwise_max(mm, nd);
            }
            float lmax = fmaxf(mm.x, mm.y);

            // local first-occurrence index of lmax (always exists)
            int ci = 0x7fffffff;
#pragma unroll
            for (int j = 0; j < 8; ++j) {
                if (dmn[j].x == lmax) ci = min(ci, base + (j << 1));
                if (dmn[j].y == lmax) ci = min(ci, base + (j << 1) + 1);
            }

            // packed: value bits (non-negative -> monotone) | (8191 - idx)
            unsigned long long pk =
                ((unsigned long long)__float_as_uint(lmax) << 32) | (unsigned)(8191 - ci);

            // wave max via DPP (VALU pipe): row_shr 1,2,4,8 then row_bcast15/31
            pk = dpp_max_step<0x111>(pk);
            pk = dpp_max_step<0x112>(pk);
            pk = dpp_max_step<0x114>(pk);
            pk = dpp_max_step<0x118>(pk);
            pk = dpp_max_step<0x142>(pk);
            pk = dpp_max_step<0x143>(pk);  // lane 63 holds wave max

            if ((tid & 63) == 63) wslot[it & 1][tid >> 6] = pk;
            __syncthreads();  // the single barrier

            ulonglong2 s01 = *(const ulonglong2*)&wslot[it & 1][0];
            ulonglong2 s23 = *(const ulonglong2*)&wslot[it & 1][2];
            ulonglong2 s45 = *(const ulonglong2*)&wslot[it & 1][4];
            ulonglong2 s67 = *(const ulonglong2*)&wslot[it & 1][6];
            unsigned long long g = s01.x;
            if (s01.y > g) g = s01.y;
            if (s23.x > g) g = s23.x;
            if (s23.y > g) g = s23.y;
            if (s45.x > g) g = s45.x;
            if (s45.y > g) g = s45.y;
            if (s67.x > g) g = s67.x;
            if (s67.y > g) g = s67.y;
            far = 8191 - (int)(unsigned)(g & 0xffffffffull);
        }
    }
}

// ---------------------------------------------------------------------------
// Ball query: one wave per query (4 queries / 256-thread block).
// First NSAMP indices in ascending index order with d2 < R^2; pad with first.
// ---------------------------------------------------------------------------
__global__ __launch_bounds__(256) void ballq_kernel(const float* __restrict__ xyz,
                                                    const float* __restrict__ new_xyz,
                                                    int* __restrict__ idxout) {
    const int tid  = threadIdx.x;
    const int lane = tid & 63;
    const int q    = (blockIdx.x << 2) + (tid >> 6);
    const int b    = q >> 10;
    const float* xb = xyz + (size_t)b * KPTS * 3;
    const float qx = new_xyz[q * 3 + 0];
    const float qy = new_xyz[q * 3 + 1];
    const float qz = new_xyz[q * 3 + 2];
    int* op = idxout + q * NSAMP;

    int total = 0;
    int first_p = 0;
    for (int c = 0; c < KPTS / 64; ++c) {
        int p = (c << 6) + lane;
        float pxv = xb[p * 3 + 0], pyv = xb[p * 3 + 1], pzv = xb[p * 3 + 2];
        float dx = __fsub_rn(qx, pxv), dy = __fsub_rn(qy, pyv), dz = __fsub_rn(qz, pzv);
        float d2 = __fadd_rn(__fadd_rn(__fmul_rn(dx, dx), __fmul_rn(dy, dy)),
                             __fmul_rn(dz, dz));
        bool pred = d2 < RAD2;
        unsigned long long mask = __ballot(pred);
        if (total == 0 && mask != 0ull) first_p = (c << 6) + (int)__builtin_ctzll(mask);
        if (pred) {
            int rank = (int)__popcll(mask & ((1ull << lane) - 1ull));
            int slot = total + rank;
            if (slot < NSAMP) op[slot] = p;
        }
        total += (int)__popcll(mask);
        if (total >= NSAMP) break;
    }
    if (total < NSAMP && lane >= total && lane < NSAMP) op[lane] = first_p;
}

// ---------------------------------------------------------------------------
// Fused gather + BN0/ReLU + two 128x128 layers (in-place LDS) + maxpool.
// 4 queries (64 rows) per 256-thread block.
// ---------------------------------------------------------------------------
#define HS 129  // LDS row stride for h

__global__ __launch_bounds__(256) void mlp_kernel(
    const float* __restrict__ f0, const int* __restrict__ idxw,
    const float* __restrict__ xyz, const float* __restrict__ new_xyz,
    const float* __restrict__ w0,
    const float* __restrict__ g0, const float* __restrict__ b0,
    const float* __restrict__ m0, const float* __restrict__ v0,
    const float* __restrict__ w1,
    const float* __restrict__ g1, const float* __restrict__ b1a,
    const float* __restrict__ m1, const float* __restrict__ v1,
    const float* __restrict__ w2,
    const float* __restrict__ g2, const float* __restrict__ b2a,
    const float* __restrict__ m2, const float* __restrict__ v2,
    float* __restrict__ featout) {
    const int tid = threadIdx.x;
    const int q0  = blockIdx.x << 2;
    const int b   = q0 >> 10;

    __shared__ float h[64 * HS];
    __shared__ float Wsh[16 * HS];
    __shared__ float gx[64], gy[64], gz[64];
    __shared__ int   pidx[64];
    __shared__ float s0[128], t0[128], wxs[128], wys[128], wzs[128];
    __shared__ float s1[128], t1[128], s2[128], t2[128];

    if (tid < 64) pidx[tid] = idxw[(q0 + (tid >> 4)) * NSAMP + (tid & 15)];
    if (tid < 128) {
        float sc = g0[tid] / sqrtf(v0[tid] + 1e-5f);
        s0[tid] = sc; t0[tid] = b0[tid] - m0[tid] * sc;
        sc = g1[tid] / sqrtf(v1[tid] + 1e-5f);
        s1[tid] = sc; t1[tid] = b1a[tid] - m1[tid] * sc;
        sc = g2[tid] / sqrtf(v2[tid] + 1e-5f);
        s2[tid] = sc; t2[tid] = b2a[tid] - m2[tid] * sc;
        wxs[tid] = w0[tid * 259 + 0];
        wys[tid] = w0[tid * 259 + 1];
        wzs[tid] = w0[tid * 259 + 2];
    }
    __syncthreads();
    if (tid < 64) {
        int p = pidx[tid];
        int q = q0 + (tid >> 4);
        const float* pp = xyz + ((size_t)b * KPTS + p) * 3;
        const float* nq = new_xyz + (size_t)q * 3;
        gx[tid] = (pp[0] - nq[0]) / 0.3f;
        gy[tid] = (pp[1] - nq[1]) / 0.3f;
        gz[tid] = (pp[2] - nq[2]) / 0.3f;
    }
    __syncthreads();

    // Phase A: gather F0 rows + xyz contribution + BN0 + ReLU
#pragma unroll 4
    for (int i = 0; i < 32; ++i) {
        int e = tid + (i << 8);
        int row = e >> 7, o = e & 127;
        int p = pidx[row];
        float v = f0[((size_t)b * KPTS + p) * 128 + o];
        v = fmaf(wxs[o], gx[row], v);
        v = fmaf(wys[o], gy[row], v);
        v = fmaf(wzs[o], gz[row], v);
        v = fmaf(v, s0[o], t0[o]);
        h[row * HS + o] = fmaxf(v, 0.f);
    }
    __syncthreads();

    // Layers 1,2: 64x128 @ 128x128, in-place on h
    const int rb = (tid >> 4) << 2;
    const int ob = tid & 15;
    for (int layer = 0; layer < 2; ++layer) {
        const float* wmat = (layer == 0) ? w1 : w2;
        const float* ssp  = (layer == 0) ? s1 : s2;
        const float* ttp  = (layer == 0) ? t1 : t2;
        float acc[4][8];
#pragma unroll
        for (int r = 0; r < 4; ++r)
#pragma unroll
            for (int c = 0; c < 8; ++c) acc[r][c] = 0.f;

        for (int k0 = 0; k0 < 128; k0 += 16) {
#pragma unroll
            for (int i = 0; i < 8; ++i) {
                int e = tid + (i << 8);
                int o = e >> 4, kk = e & 15;
                Wsh[kk * HS + o] = wmat[o * 128 + k0 + kk];
            }
            __syncthreads();
#pragma unroll
            for (int kk = 0; kk < 16; ++kk) {
                float a[4], wvv[8];
#pragma unroll
                for (int r = 0; r < 4; ++r) a[r] = h[(rb + r) * HS + k0 + kk];
#pragma unroll
                for (int c = 0; c < 8; ++c) wvv[c] = Wsh[kk * HS + ob + (c << 4)];
#pragma unroll
                for (int r = 0; r < 4; ++r)
#pragma unroll
                    for (int c = 0; c < 8; ++c) acc[r][c] = fmaf(a[r], wvv[c], acc[r][c]);
            }
            __syncthreads();
        }
#pragma unroll
        for (int r = 0; r < 4; ++r)
#pragma unroll
            for (int c = 0; c < 8; ++c) {
                int o = ob + (c << 4);
                float v = fmaf(acc[r][c], ssp[o], ttp[o]);
                h[(rb + r) * HS + o] = fmaxf(v, 0.f);
            }
        __syncthreads();
    }

    // maxpool over the 16 samples per query
#pragma unroll
    for (int i = 0; i < 2; ++i) {
        int e = tid + (i << 8);
        int qq = e >> 7, o = e & 127;
        float m = h[(qq * 16) * HS + o];
#pragma unroll
        for (int n = 1; n < 16; ++n) m = fmaxf(m, h[(qq * 16 + n) * HS + o]);
        featout[(size_t)(q0 + qq) * 128 + o] = m;
    }
}

// ---------------------------------------------------------------------------
// Head: FC1(bn,relu) -> FC2(bn,relu) -> FC3 + output assembly.
// ---------------------------------------------------------------------------
__global__ __launch_bounds__(256) void head_kernel(
    const float* __restrict__ feat, const float* __restrict__ new_xyz,
    const float* __restrict__ c1w, const float* __restrict__ c1b,
    const float* __restrict__ c2w, const float* __restrict__ c2b,
    const float* __restrict__ c3w, const float* __restrict__ c3b,
    const float* __restrict__ bg1, const float* __restrict__ bb1,
    const float* __restrict__ bm1, const float* __restrict__ bv1,
    const float* __restrict__ bg2, const float* __restrict__ bb2,
    const float* __restrict__ bm2, const float* __restrict__ bv2,
    const float* __restrict__ msz, float* __restrict__ out) {
    const int tid = threadIdx.x;
    const int q0  = blockIdx.x << 3;
    __shared__ float fs[8][128], n1[8][128], n2[8][128];
    __shared__ float s1[128], t1[128], s2[128], t2[128], ms[54];

#pragma unroll
    for (int i = 0; i < 4; ++i) {
        int e = tid + (i << 8);
        fs[e >> 7][e & 127] = feat[(size_t)q0 * 128 + e];
    }
    if (tid < 128) {
        float sc = bg1[tid] / sqrtf(bv1[tid] + 1e-5f);
        s1[tid] = sc; t1[tid] = bb1[tid] - bm1[tid] * sc;
        sc = bg2[tid] / sqrtf(bv2[tid] + 1e-5f);
        s2[tid] = sc; t2[tid] = bb2[tid] - bm2[tid] * sc;
    }
    if (tid < 54) ms[tid] = msz[tid];
    __syncthreads();

    const int o    = tid & 127;
    const int half = tid >> 7;

    {
        float a[4];
#pragma unroll
        for (int j = 0; j < 4; ++j) a[j] = c1b[o];
        const float* wr = c1w + o * 128;
        for (int k = 0; k < 128; k += 4) {
            float4 w4 = *(const float4*)(wr + k);
#pragma unroll
            for (int j = 0; j < 4; ++j) {
                int qq = half * 4 + j;
                a[j] = fmaf(fs[qq][k + 0], w4.x, a[j]);
                a[j] = fmaf(fs[qq][k + 1], w4.y, a[j]);
                a[j] = fmaf(fs[qq][k + 2], w4.z, a[j]);
                a[j] = fmaf(fs[qq][k + 3], w4.w, a[j]);
            }
        }
#pragma unroll
        for (int j = 0; j < 4; ++j)
            n1[half * 4 + j][o] = fmaxf(fmaf(a[j], s1[o], t1[o]), 0.f);
    }
    __syncthreads();
    {
        float a[4];
#pragma unroll
        for (int j = 0; j < 4; ++j) a[j] = c2b[o];
        const float* wr = c2w + o * 128;
        for (int k = 0; k < 128; k += 4) {
            float4 w4 = *(const float4*)(wr + k);
#pragma unroll
            for (int j = 0; j < 4; ++j) {
                int qq = half * 4 + j;
                a[j] = fmaf(n1[qq][k + 0], w4.x, a[j]);
                a[j] = fmaf(n1[qq][k + 1], w4.y, a[j]);
                a[j] = fmaf(n1[qq][k + 2], w4.z, a[j]);
                a[j] = fmaf(n1[qq][k + 3], w4.w, a[j]);
            }
        }
#pragma unroll
        for (int j = 0; j < 4; ++j)
            n2[half * 4 + j][o] = fmaxf(fmaf(a[j], s2[o], t2[o]), 0.f);
    }
    __syncthreads();
    if (o < 97) {
        float a[4];
#pragma unroll
        for (int j = 0; j < 4; ++j) a[j] = c3b[o];
        const float* wr = c3w + o * 128;
        for (int k = 0; k < 128; k += 4) {
            float4 w4 = *(const float4*)(wr + k);
#pragma unroll
            for (int j = 0; j < 4; ++j) {
                int qq = half * 4 + j;
                a[j] = fmaf(n2[qq][k + 0], w4.x, a[j]);
                a[j] = fmaf(n2[qq][k + 1], w4.y, a[j]);
                a[j] = fmaf(n2[qq][k + 2], w4.z, a[j]);
                a[j] = fmaf(n2[qq][k + 3], w4.w, a[j]);
            }
        }
#pragma unroll
        for (int j = 0; j < 4; ++j) {
            int q = q0 + half * 4 + j;
            float v = a[j];
            if (o >= 2 && o < 5) v += new_xyz[(size_t)q * 3 + (o - 2)];
            else if (o == 6) v *= 3.14159265358979323846f;  // * (pi/NH), NH=1
            else if (o >= 25 && o < 79) v *= ms[o - 25];    // sr * mean_size
            out[(size_t)q * 97 + o] = v;
        }
    }
}

// ---------------------------------------------------------------------------
extern "C" void kernel_launch(void* const* d_in, const int* in_sizes, int n_in,
                              void* d_out, int out_size, void* d_ws, size_t ws_size,
                              hipStream_t stream) {
    const float* xyz      = (const float*)d_in[0];
    const float* features = (const float*)d_in[1];
    const float* w0  = (const float*)d_in[2];
    const float* g0  = (const float*)d_in[3];
    const float* b0  = (const float*)d_in[4];
    const float* m0  = (const float*)d_in[5];
    const float* v0  = (const float*)d_in[6];
    const float* w1  = (const float*)d_in[7];
    const float* g1  = (const float*)d_in[8];
    const float* b1  = (const float*)d_in[9];
    const float* m1  = (const float*)d_in[10];
    const float* v1  = (const float*)d_in[11];
    const float* w2  = (const float*)d_in[12];
    const float* g2  = (const float*)d_in[13];
    const float* b2  = (const float*)d_in[14];
    const float* m2  = (const float*)d_in[15];
    const float* v2  = (const float*)d_in[16];
    const float* c1w = (const float*)d_in[17];
    const float* c1b = (const float*)d_in[18];
    const float* c2w = (const float*)d_in[19];
    const float* c2b = (const float*)d_in[20];
    const float* c3w = (const float*)d_in[21];
    const float* c3b = (const float*)d_in[22];
    const float* bg1 = (const float*)d_in[23];
    const float* bb1 = (const float*)d_in[24];
    const float* bm1 = (const float*)d_in[25];
    const float* bv1 = (const float*)d_in[26];
    const float* bg2 = (const float*)d_in[27];
    const float* bb2 = (const float*)d_in[28];
    const float* bm2 = (const float*)d_in[29];
    const float* bv2 = (const float*)d_in[30];
    const float* msz = (const float*)d_in[31];

    float* F0   = (float*)d_ws;
    float* feat = F0 + (size_t)BATCH * KPTS * 128;
    int*   idxw = (int*)(feat + (size_t)BATCH * NPT * 128);
    float* nxyz = (float*)(idxw + (size_t)BATCH * NPT * NSAMP);
    float* outp = (float*)d_out;

    fps_f0_kernel<<<8 + BATCH * (KPTS / 128), 512, 0, stream>>>(
        xyz, nxyz, features, w0, F0);
    ballq_kernel<<<BATCH * NPT / 4, 256, 0, stream>>>(xyz, nxyz, idxw);
    mlp_kernel  <<<BATCH * NPT / 4, 256, 0, stream>>>(
        F0, idxw, xyz, nxyz, w0, g0, b0, m0, v0,
        w1, g1, b1, m1, v1, w2, g2, b2, m2, v2, feat);
    head_kernel <<<BATCH * NPT / 8, 256, 0, stream>>>(
        feat, nxyz, c1w, c1b, c2w, c2b, c3w, c3b,
        bg1, bb1, bm1, bv1, bg2, bb2, bm2, bv2, msz, outp);
}

// Round 6
// 1424.022 us; speedup vs baseline: 1.0078x; 1.0078x over previous
//
#include <hip/hip_runtime.h>
#include <cstdint>
#include <cstddef>

// Problem constants
#define BATCH   8
#define KPTS    8192
#define NPT     1024
#define NSAMP   16
#define RAD2    0.09f

typedef float f32x2 __attribute__((ext_vector_type(2)));

// DPP max-reduce step for packed u64 (hi=float bits, lo=8191-idx).
// bound_ctrl=true -> out-of-range source lanes read 0 (neutral for unsigned max).
template <int CTRL>
__device__ __forceinline__ unsigned long long dpp_max_step(unsigned long long v) {
    unsigned int lo = (unsigned int)v, hi = (unsigned int)(v >> 32);
    unsigned int lo2 = (unsigned int)__builtin_amdgcn_update_dpp(0, (int)lo, CTRL, 0xf, 0xf, true);
    unsigned int hi2 = (unsigned int)__builtin_amdgcn_update_dpp(0, (int)hi, CTRL, 0xf, 0xf, true);
    unsigned long long o = ((unsigned long long)hi2 << 32) | lo2;
    return o > v ? o : v;
}

// ---------------------------------------------------------------------------
// Fused FPS + F0 dispatch, 512 threads/block.
// Blocks 0..7: FPS (one per batch, 16 pts/thread, coords register-resident).
// Blocks 8..519: F0 pre-gather GEMM tiles (128x128, 4x8 acc/thread).
// FPS loop contains ZERO global-memory ops: selected indices go to an LDS
// history array; new_xyz is written in an epilogue. (R5 post-mortem: the
// in-loop tid0 global store forced s_waitcnt vmcnt(0) before every barrier —
// an HBM store-ack on the serial chain each iteration.)
// Packed-u64 DPP argmax (value + smallest index = NumPy first-occurrence),
// ONE barrier/iter with ping-pong slots. Distance math float2 IEEE
// contract(off) == NumPy rounding exactly.
// ---------------------------------------------------------------------------
__global__ __launch_bounds__(512, 1) void fps_f0_kernel(
    const float* __restrict__ xyz, float* __restrict__ new_xyz,
    const float* __restrict__ feats, const float* __restrict__ w0,
    float* __restrict__ f0out) {
    __shared__ float xs[KPTS], ys[KPTS], zs[KPTS];               // 96 KB (fps)
    __shared__ __align__(16) unsigned long long wslot[2][8];
    __shared__ int   hist[NPT];                                   // 4 KB (fps)
    __shared__ float As[16 * 128];                                // f0
    __shared__ float Bs[16 * 130];                                // f0

    const int tid = threadIdx.x;

    if (blockIdx.x >= 8) {
        // ---------------- F0 GEMM: F0[b,p,o] = sum_c feats[b,c,p]*w0[o,3+c]
        const int bid = blockIdx.x - 8;
        const int b   = bid >> 6;
        const int p0  = (bid & 63) << 7;
        const int rb  = (tid >> 4) << 2;  // 4 rows (points), 0..124
        const int ob  = tid & 15;         // col base; cols = ob + 16*c
        const float* fb = feats + (size_t)b * 256 * KPTS;

        float acc[4][8];
#pragma unroll
        for (int r = 0; r < 4; ++r)
#pragma unroll
            for (int c = 0; c < 8; ++c) acc[r][c] = 0.f;

        for (int k0 = 0; k0 < 256; k0 += 16) {
#pragma unroll
            for (int i = 0; i < 4; ++i) {
                int e = tid + (i << 9);
                int kk = e >> 7, pc = e & 127;
                As[kk * 128 + pc] = fb[(size_t)(k0 + kk) * KPTS + p0 + pc];
            }
#pragma unroll
            for (int i = 0; i < 4; ++i) {
                int e = tid + (i << 9);
                int o = e >> 4, kk = e & 15;
                Bs[kk * 130 + o] = w0[o * 259 + 3 + k0 + kk];
            }
            __syncthreads();
#pragma unroll
            for (int kk = 0; kk < 16; ++kk) {
                float a[4], wvv[8];
#pragma unroll
                for (int r = 0; r < 4; ++r) a[r] = As[kk * 128 + rb + r];
#pragma unroll
                for (int c = 0; c < 8; ++c) wvv[c] = Bs[kk * 130 + ob + (c << 4)];
#pragma unroll
                for (int r = 0; r < 4; ++r)
#pragma unroll
                    for (int c = 0; c < 8; ++c) acc[r][c] = fmaf(a[r], wvv[c], acc[r][c]);
            }
            __syncthreads();
        }
#pragma unroll
        for (int r = 0; r < 4; ++r) {
            float* outp = f0out + ((size_t)b * KPTS + p0 + rb + r) * 128 + ob;
#pragma unroll
            for (int c = 0; c < 8; ++c) outp[c << 4] = acc[r][c];
        }
        return;
    }

    // ---------------- FPS ----------------
    {
#pragma clang fp contract(off)
        const int b = blockIdx.x;
        const float* xb = xyz + (size_t)b * KPTS * 3;

        for (int i = tid; i < KPTS; i += 512) {
            xs[i] = xb[i * 3 + 0];
            ys[i] = xb[i * 3 + 1];
            zs[i] = xb[i * 3 + 2];
        }
        __syncthreads();

        const int base = tid << 4;  // 16 points per thread (8 float2 pairs)
        f32x2 px[8], py[8], pz[8], dmn[8];
#pragma unroll
        for (int j = 0; j < 8; ++j) {
            int i0 = base + (j << 1);
            px[j] = (f32x2){xs[i0], xs[i0 + 1]};
            py[j] = (f32x2){ys[i0], ys[i0 + 1]};
            pz[j] = (f32x2){zs[i0], zs[i0 + 1]};
            dmn[j] = (f32x2){1e10f, 1e10f};
        }

        int far = 0;
        for (int it = 0; it < NPT; ++it) {
            if (tid == 0) hist[it] = far;   // LDS only — off the vmcnt path
            const float cx = xs[far], cy = ys[far], cz = zs[far];
            const f32x2 cx2 = (f32x2){cx, cx};
            const f32x2 cy2 = (f32x2){cy, cy};
            const f32x2 cz2 = (f32x2){cz, cz};

            f32x2 mm = (f32x2){-1.0f, -1.0f};
#pragma unroll
            for (int j = 0; j < 8; ++j) {
                f32x2 dx = px[j] - cx2;
                f32x2 dy = py[j] - cy2;
                f32x2 dz = pz[j] - cz2;
                f32x2 d  = (dx * dx + dy * dy) + dz * dz;  // rounded squares, seq adds
                f32x2 nd = __builtin_elementwise_min(dmn[j], d);
                dmn[j] = nd;
                mm = __builtin_elementwise_max(mm, nd);
            }
            float lmax = fmaxf(mm.x, mm.y);

            // local first-occurrence index of lmax (always exists)
            int ci = 0x7fffffff;
#pragma unroll
            for (int j = 0; j < 8; ++j) {
                if (dmn[j].x == lmax) ci = min(ci, base + (j << 1));
                if (dmn[j].y == lmax) ci = min(ci, base + (j << 1) + 1);
            }

            // packed: value bits (non-negative -> monotone) | (8191 - idx)
            unsigned long long pk =
                ((unsigned long long)__float_as_uint(lmax) << 32) | (unsigned)(8191 - ci);

            // wave max via DPP (VALU pipe): row_shr 1,2,4,8 then row_bcast15/31
            pk = dpp_max_step<0x111>(pk);
            pk = dpp_max_step<0x112>(pk);
            pk = dpp_max_step<0x114>(pk);
            pk = dpp_max_step<0x118>(pk);
            pk = dpp_max_step<0x142>(pk);
            pk = dpp_max_step<0x143>(pk);  // lane 63 holds wave max

            if ((tid & 63) == 63) wslot[it & 1][tid >> 6] = pk;
            __syncthreads();  // the single barrier (lgkm-only drain now)

            ulonglong2 s01 = *(const ulonglong2*)&wslot[it & 1][0];
            ulonglong2 s23 = *(const ulonglong2*)&wslot[it & 1][2];
            ulonglong2 s45 = *(const ulonglong2*)&wslot[it & 1][4];
            ulonglong2 s67 = *(const ulonglong2*)&wslot[it & 1][6];
            unsigned long long g = s01.x;
            if (s01.y > g) g = s01.y;
            if (s23.x > g) g = s23.x;
            if (s23.y > g) g = s23.y;
            if (s45.x > g) g = s45.x;
            if (s45.y > g) g = s45.y;
            if (s67.x > g) g = s67.x;
            if (s67.y > g) g = s67.y;
            far = 8191 - (int)(unsigned)(g & 0xffffffffull);
        }

        // Epilogue: write all selected coordinates (hist visible via the
        // loop's final barrier).
        for (int i = tid; i < NPT; i += 512) {
            int idx = hist[i];
            float* o = new_xyz + ((size_t)b * NPT + i) * 3;
            o[0] = xs[idx]; o[1] = ys[idx]; o[2] = zs[idx];
        }
    }
}

// ---------------------------------------------------------------------------
// Ball query: one wave per query (4 queries / 256-thread block).
// First NSAMP indices in ascending index order with d2 < R^2; pad with first.
// ---------------------------------------------------------------------------
__global__ __launch_bounds__(256) void ballq_kernel(const float* __restrict__ xyz,
                                                    const float* __restrict__ new_xyz,
                                                    int* __restrict__ idxout) {
    const int tid  = threadIdx.x;
    const int lane = tid & 63;
    const int q    = (blockIdx.x << 2) + (tid >> 6);
    const int b    = q >> 10;
    const float* xb = xyz + (size_t)b * KPTS * 3;
    const float qx = new_xyz[q * 3 + 0];
    const float qy = new_xyz[q * 3 + 1];
    const float qz = new_xyz[q * 3 + 2];
    int* op = idxout + q * NSAMP;

    int total = 0;
    int first_p = 0;
    for (int c = 0; c < KPTS / 64; ++c) {
        int p = (c << 6) + lane;
        float pxv = xb[p * 3 + 0], pyv = xb[p * 3 + 1], pzv = xb[p * 3 + 2];
        float dx = __fsub_rn(qx, pxv), dy = __fsub_rn(qy, pyv), dz = __fsub_rn(qz, pzv);
        float d2 = __fadd_rn(__fadd_rn(__fmul_rn(dx, dx), __fmul_rn(dy, dy)),
                             __fmul_rn(dz, dz));
        bool pred = d2 < RAD2;
        unsigned long long mask = __ballot(pred);
        if (total == 0 && mask != 0ull) first_p = (c << 6) + (int)__builtin_ctzll(mask);
        if (pred) {
            int rank = (int)__popcll(mask & ((1ull << lane) - 1ull));
            int slot = total + rank;
            if (slot < NSAMP) op[slot] = p;
        }
        total += (int)__popcll(mask);
        if (total >= NSAMP) break;
    }
    if (total < NSAMP && lane >= total && lane < NSAMP) op[lane] = first_p;
}

// ---------------------------------------------------------------------------
// Fused gather + BN0/ReLU + two 128x128 layers (in-place LDS) + maxpool.
// 4 queries (64 rows) per 256-thread block.
// ---------------------------------------------------------------------------
#define HS 129  // LDS row stride for h

__global__ __launch_bounds__(256) void mlp_kernel(
    const float* __restrict__ f0, const int* __restrict__ idxw,
    const float* __restrict__ xyz, const float* __restrict__ new_xyz,
    const float* __restrict__ w0,
    const float* __restrict__ g0, const float* __restrict__ b0,
    const float* __restrict__ m0, const float* __restrict__ v0,
    const float* __restrict__ w1,
    const float* __restrict__ g1, const float* __restrict__ b1a,
    const float* __restrict__ m1, const float* __restrict__ v1,
    const float* __restrict__ w2,
    const float* __restrict__ g2, const float* __restrict__ b2a,
    const float* __restrict__ m2, const float* __restrict__ v2,
    float* __restrict__ featout) {
    const int tid = threadIdx.x;
    const int q0  = blockIdx.x << 2;
    const int b   = q0 >> 10;

    __shared__ float h[64 * HS];
    __shared__ float Wsh[16 * HS];
    __shared__ float gx[64], gy[64], gz[64];
    __shared__ int   pidx[64];
    __shared__ float s0[128], t0[128], wxs[128], wys[128], wzs[128];
    __shared__ float s1[128], t1[128], s2[128], t2[128];

    if (tid < 64) pidx[tid] = idxw[(q0 + (tid >> 4)) * NSAMP + (tid & 15)];
    if (tid < 128) {
        float sc = g0[tid] / sqrtf(v0[tid] + 1e-5f);
        s0[tid] = sc; t0[tid] = b0[tid] - m0[tid] * sc;
        sc = g1[tid] / sqrtf(v1[tid] + 1e-5f);
        s1[tid] = sc; t1[tid] = b1a[tid] - m1[tid] * sc;
        sc = g2[tid] / sqrtf(v2[tid] + 1e-5f);
        s2[tid] = sc; t2[tid] = b2a[tid] - m2[tid] * sc;
        wxs[tid] = w0[tid * 259 + 0];
        wys[tid] = w0[tid * 259 + 1];
        wzs[tid] = w0[tid * 259 + 2];
    }
    __syncthreads();
    if (tid < 64) {
        int p = pidx[tid];
        int q = q0 + (tid >> 4);
        const float* pp = xyz + ((size_t)b * KPTS + p) * 3;
        const float* nq = new_xyz + (size_t)q * 3;
        gx[tid] = (pp[0] - nq[0]) / 0.3f;
        gy[tid] = (pp[1] - nq[1]) / 0.3f;
        gz[tid] = (pp[2] - nq[2]) / 0.3f;
    }
    __syncthreads();

    // Phase A: gather F0 rows + xyz contribution + BN0 + ReLU
#pragma unroll 4
    for (int i = 0; i < 32; ++i) {
        int e = tid + (i << 8);
        int row = e >> 7, o = e & 127;
        int p = pidx[row];
        float v = f0[((size_t)b * KPTS + p) * 128 + o];
        v = fmaf(wxs[o], gx[row], v);
        v = fmaf(wys[o], gy[row], v);
        v = fmaf(wzs[o], gz[row], v);
        v = fmaf(v, s0[o], t0[o]);
        h[row * HS + o] = fmaxf(v, 0.f);
    }
    __syncthreads();

    // Layers 1,2: 64x128 @ 128x128, in-place on h
    const int rb = (tid >> 4) << 2;
    const int ob = tid & 15;
    for (int layer = 0; layer < 2; ++layer) {
        const float* wmat = (layer == 0) ? w1 : w2;
        const float* ssp  = (layer == 0) ? s1 : s2;
        const float* ttp  = (layer == 0) ? t1 : t2;
        float acc[4][8];
#pragma unroll
        for (int r = 0; r < 4; ++r)
#pragma unroll
            for (int c = 0; c < 8; ++c) acc[r][c] = 0.f;

        for (int k0 = 0; k0 < 128; k0 += 16) {
#pragma unroll
            for (int i = 0; i < 8; ++i) {
                int e = tid + (i << 8);
                int o = e >> 4, kk = e & 15;
                Wsh[kk * HS + o] = wmat[o * 128 + k0 + kk];
            }
            __syncthreads();
#pragma unroll
            for (int kk = 0; kk < 16; ++kk) {
                float a[4], wvv[8];
#pragma unroll
                for (int r = 0; r < 4; ++r) a[r] = h[(rb + r) * HS + k0 + kk];
#pragma unroll
                for (int c = 0; c < 8; ++c) wvv[c] = Wsh[kk * HS + ob + (c << 4)];
#pragma unroll
                for (int r = 0; r < 4; ++r)
#pragma unroll
                    for (int c = 0; c < 8; ++c) acc[r][c] = fmaf(a[r], wvv[c], acc[r][c]);
            }
            __syncthreads();
        }
#pragma unroll
        for (int r = 0; r < 4; ++r)
#pragma unroll
            for (int c = 0; c < 8; ++c) {
                int o = ob + (c << 4);
                float v = fmaf(acc[r][c], ssp[o], ttp[o]);
                h[(rb + r) * HS + o] = fmaxf(v, 0.f);
            }
        __syncthreads();
    }

    // maxpool over the 16 samples per query
#pragma unroll
    for (int i = 0; i < 2; ++i) {
        int e = tid + (i << 8);
        int qq = e >> 7, o = e & 127;
        float m = h[(qq * 16) * HS + o];
#pragma unroll
        for (int n = 1; n < 16; ++n) m = fmaxf(m, h[(qq * 16 + n) * HS + o]);
        featout[(size_t)(q0 + qq) * 128 + o] = m;
    }
}

// ---------------------------------------------------------------------------
// Head: FC1(bn,relu) -> FC2(bn,relu) -> FC3 + output assembly.
// ---------------------------------------------------------------------------
__global__ __launch_bounds__(256) void head_kernel(
    const float* __restrict__ feat, const float* __restrict__ new_xyz,
    const float* __restrict__ c1w, const float* __restrict__ c1b,
    const float* __restrict__ c2w, const float* __restrict__ c2b,
    const float* __restrict__ c3w, const float* __restrict__ c3b,
    const float* __restrict__ bg1, const float* __restrict__ bb1,
    const float* __restrict__ bm1, const float* __restrict__ bv1,
    const float* __restrict__ bg2, const float* __restrict__ bb2,
    const float* __restrict__ bm2, const float* __restrict__ bv2,
    const float* __restrict__ msz, float* __restrict__ out) {
    const int tid = threadIdx.x;
    const int q0  = blockIdx.x << 3;
    __shared__ float fs[8][128], n1[8][128], n2[8][128];
    __shared__ float s1[128], t1[128], s2[128], t2[128], ms[54];

#pragma unroll
    for (int i = 0; i < 4; ++i) {
        int e = tid + (i << 8);
        fs[e >> 7][e & 127] = feat[(size_t)q0 * 128 + e];
    }
    if (tid < 128) {
        float sc = bg1[tid] / sqrtf(bv1[tid] + 1e-5f);
        s1[tid] = sc; t1[tid] = bb1[tid] - bm1[tid] * sc;
        sc = bg2[tid] / sqrtf(bv2[tid] + 1e-5f);
        s2[tid] = sc; t2[tid] = bb2[tid] - bm2[tid] * sc;
    }
    if (tid < 54) ms[tid] = msz[tid];
    __syncthreads();

    const int o    = tid & 127;
    const int half = tid >> 7;

    {
        float a[4];
#pragma unroll
        for (int j = 0; j < 4; ++j) a[j] = c1b[o];
        const float* wr = c1w + o * 128;
        for (int k = 0; k < 128; k += 4) {
            float4 w4 = *(const float4*)(wr + k);
#pragma unroll
            for (int j = 0; j < 4; ++j) {
                int qq = half * 4 + j;
                a[j] = fmaf(fs[qq][k + 0], w4.x, a[j]);
                a[j] = fmaf(fs[qq][k + 1], w4.y, a[j]);
                a[j] = fmaf(fs[qq][k + 2], w4.z, a[j]);
                a[j] = fmaf(fs[qq][k + 3], w4.w, a[j]);
            }
        }
#pragma unroll
        for (int j = 0; j < 4; ++j)
            n1[half * 4 + j][o] = fmaxf(fmaf(a[j], s1[o], t1[o]), 0.f);
    }
    __syncthreads();
    {
        float a[4];
#pragma unroll
        for (int j = 0; j < 4; ++j) a[j] = c2b[o];
        const float* wr = c2w + o * 128;
        for (int k = 0; k < 128; k += 4) {
            float4 w4 = *(const float4*)(wr + k);
#pragma unroll
            for (int j = 0; j < 4; ++j) {
                int qq = half * 4 + j;
                a[j] = fmaf(n1[qq][k + 0], w4.x, a[j]);
                a[j] = fmaf(n1[qq][k + 1], w4.y, a[j]);
                a[j] = fmaf(n1[qq][k + 2], w4.z, a[j]);
                a[j] = fmaf(n1[qq][k + 3], w4.w, a[j]);
            }
        }
#pragma unroll
        for (int j = 0; j < 4; ++j)
            n2[half * 4 + j][o] = fmaxf(fmaf(a[j], s2[o], t2[o]), 0.f);
    }
    __syncthreads();
    if (o < 97) {
        float a[4];
#pragma unroll
        for (int j = 0; j < 4; ++j) a[j] = c3b[o];
        const float* wr = c3w + o * 128;
        for (int k = 0; k < 128; k += 4) {
            float4 w4 = *(const float4*)(wr + k);
#pragma unroll
            for (int j = 0; j < 4; ++j) {
                int qq = half * 4 + j;
                a[j] = fmaf(n2[qq][k + 0], w4.x, a[j]);
                a[j] = fmaf(n2[qq][k + 1], w4.y, a[j]);
                a[j] = fmaf(n2[qq][k + 2], w4.z, a[j]);
                a[j] = fmaf(n2[qq][k + 3], w4.w, a[j]);
            }
        }
#pragma unroll
        for (int j = 0; j < 4; ++j) {
            int q = q0 + half * 4 + j;
            float v = a[j];
            if (o >= 2 && o < 5) v += new_xyz[(size_t)q * 3 + (o - 2)];
            else if (o == 6) v *= 3.14159265358979323846f;  // * (pi/NH), NH=1
            else if (o >= 25 && o < 79) v *= ms[o - 25];    // sr * mean_size
            out[(size_t)q * 97 + o] = v;
        }
    }
}

// ---------------------------------------------------------------------------
extern "C" void kernel_launch(void* const* d_in, const int* in_sizes, int n_in,
                              void* d_out, int out_size, void* d_ws, size_t ws_size,
                              hipStream_t stream) {
    const float* xyz      = (const float*)d_in[0];
    const float* features = (const float*)d_in[1];
    const float* w0  = (const float*)d_in[2];
    const float* g0  = (const float*)d_in[3];
    const float* b0  = (const float*)d_in[4];
    const float* m0  = (const float*)d_in[5];
    const float* v0  = (const float*)d_in[6];
    const float* w1  = (const float*)d_in[7];
    const float* g1  = (const float*)d_in[8];
    const float* b1  = (const float*)d_in[9];
    const float* m1  = (const float*)d_in[10];
    const float* v1  = (const float*)d_in[11];
    const float* w2  = (const float*)d_in[12];
    const float* g2  = (const float*)d_in[13];
    const float* b2  = (const float*)d_in[14];
    const float* m2  = (const float*)d_in[15];
    const float* v2  = (const float*)d_in[16];
    const float* c1w = (const float*)d_in[17];
    const float* c1b = (const float*)d_in[18];
    const float* c2w = (const float*)d_in[19];
    const float* c2b = (const float*)d_in[20];
    const float* c3w = (const float*)d_in[21];
    const float* c3b = (const float*)d_in[22];
    const float* bg1 = (const float*)d_in[23];
    const float* bb1 = (const float*)d_in[24];
    const float* bm1 = (const float*)d_in[25];
    const float* bv1 = (const float*)d_in[26];
    const float* bg2 = (const float*)d_in[27];
    const float* bb2 = (const float*)d_in[28];
    const float* bm2 = (const float*)d_in[29];
    const float* bv2 = (const float*)d_in[30];
    const float* msz = (const float*)d_in[31];

    float* F0   = (float*)d_ws;
    float* feat = F0 + (size_t)BATCH * KPTS * 128;
    int*   idxw = (int*)(feat + (size_t)BATCH * NPT * 128);
    float* nxyz = (float*)(idxw + (size_t)BATCH * NPT * NSAMP);
    float* outp = (float*)d_out;

    fps_f0_kernel<<<8 + BATCH * (KPTS / 128), 512, 0, stream>>>(
        xyz, nxyz, features, w0, F0);
    ballq_kernel<<<BATCH * NPT / 4, 256, 0, stream>>>(xyz, nxyz, idxw);
    mlp_kernel  <<<BATCH * NPT / 4, 256, 0, stream>>>(
        F0, idxw, xyz, nxyz, w0, g0, b0, m0, v0,
        w1, g1, b1, m1, v1, w2, g2, b2, m2, v2, feat);
    head_kernel <<<BATCH * NPT / 8, 256, 0, stream>>>(
        feat, nxyz, c1w, c1b, c2w, c2b, c3w, c3b,
        bg1, bb1, bm1, bv1, bg2, bb2, bm2, bv2, msz, outp);
}